// Round 14
// baseline (600.787 us; speedup 1.0000x reference)
//
#include <hip/hip_runtime.h>
#include <hip/hip_bf16.h>
#include <stdint.h>

#define N_TOK 8192
#define D_IN  2048
#define D_OUT 8192
#define NEXP  8
#define KST   32                /* D_IN / 64 */
#define NT2   40                /* max 256-row tiles */
#define NS2   32                /* 256-col strips */
#define AIMG  32768             /* one (tile|strip, kstep) image: [ks][pair-swizzled 16KB] */
#define X_OFF2 65536
#define X_BYTES2 ((long)NT2 * KST * AIMG)                /* 40 MB  */
#define W_OFF2 (X_OFF2 + X_BYTES2)
#define W_BYTES2 ((long)NEXP * NS2 * KST * AIMG)         /* 256 MB */
#define WS_NEED2 ((size_t)(W_OFF2 + W_BYTES2))

// pair-row swizzle: element (r 0..255, chunk c 0..3 [16B=8 k-elems], ks)
// byte = ks*16384 + (r>>1)*128 + ((((r&1)<<2)|c) ^ ((r>>1)&7))*16
// read group (16 lanes, r=C..C+15, fixed c): 8 slots x2 -> 2-way = free (measured 0)

typedef float  f32x4  __attribute__((ext_vector_type(4)));
typedef __bf16 bf16x8 __attribute__((ext_vector_type(8)));

__global__ void SwitchLinear_setup_kernel(const int* __restrict__ idx,
                                          int* __restrict__ ws) {
    __shared__ int cnt[NEXP], cur[NEXP];
    int t = threadIdx.x;
    if (t < NEXP) cnt[t] = 0;
    __syncthreads();
    for (int i = t; i < N_TOK; i += 256) atomicAdd(&cnt[idx[i]], 1);
    __syncthreads();
    if (t == 0) {
        int o = 0, nt = 0, nt1 = 0;
        for (int e = 0; e < NEXP; ++e) {
            cur[e] = o;
            int c = cnt[e];
            for (int r = 0; r < c; r += 256) {
                ws[8 + nt]   = e;
                ws[96 + nt]  = o + r;
                ws[192 + nt] = (c - r < 256) ? (c - r) : 256;
                ++nt;
            }
            for (int r = 0; r < c; r += 128) {
                ws[256 + nt1] = e;
                ws[328 + nt1] = o + r;
                ws[400 + nt1] = (c - r < 128) ? (c - r) : 128;
                ++nt1;
            }
            o += c;
        }
        ws[0] = nt;
        ws[4] = nt1;
    }
    __syncthreads();
    for (int i = t; i < N_TOK; i += 256) {
        int p = atomicAdd(&cur[idx[i]], 1);
        ws[512 + p] = i;
    }
}

// ---------- conversion to pre-swizzled bf16 images ------------------------

__global__ __launch_bounds__(256) void SwitchLinear_convx_kernel(
    const float* __restrict__ x, const int* __restrict__ ws,
    char* __restrict__ wsb) {
    const int tile = blockIdx.x, kst = blockIdx.y;
    if (tile >= ws[0]) return;
    const int rs = ws[96 + tile], rows = ws[192 + tile];
    char* img = wsb + X_OFF2 + (long)(tile * KST + kst) * AIMG;
    const int t = threadIdx.x;
#pragma unroll
    for (int i = 0; i < 8; ++i) {
        int u = t + i * 256;            // 0..2047
        int R = u >> 3, kc8 = u & 7;
        int rl = rs + (R < rows ? R : rows - 1);
        int token = ws[512 + rl];
        const float* src = x + (long)token * D_IN + kst * 64 + kc8 * 8;
        f32x4 v0 = *(const f32x4*)src;
        f32x4 v1 = *(const f32x4*)(src + 4);
        union { __bf16 hh[8]; uint4 u4; } c;
        c.hh[0] = (__bf16)v0[0]; c.hh[1] = (__bf16)v0[1];
        c.hh[2] = (__bf16)v0[2]; c.hh[3] = (__bf16)v0[3];
        c.hh[4] = (__bf16)v1[0]; c.hh[5] = (__bf16)v1[1];
        c.hh[6] = (__bf16)v1[2]; c.hh[7] = (__bf16)v1[3];
        int slot = (((R & 1) << 2) | (kc8 & 3)) ^ ((R >> 1) & 7);
        *(uint4*)(img + (kc8 >> 2) * 16384 + ((R >> 1) << 7) + (slot << 4)) = c.u4;
    }
}

__global__ __launch_bounds__(256) void SwitchLinear_convw_kernel(
    const float* __restrict__ w, char* __restrict__ wsb) {
    const int img = blockIdx.x;          // (e, strip128 s, kst)
    const int kst = img & 31, s = (img >> 5) & 63, e = img >> 11;
    const int y = s >> 1, hh = s & 1;
    __shared__ float tl[64 * 129];
    const float* src = w + (long)e * D_IN * D_OUT + (long)(kst * 64) * D_OUT +
                       y * 256 + hh * 128;
    const int t = threadIdx.x;
#pragma unroll
    for (int i = 0; i < 8; ++i) {
        int u = t + i * 256;
        int row = u >> 5, ch = u & 31;   // 64 k-rows x 128 cols (fp32)
        f32x4 v = *(const f32x4*)(src + (long)row * D_OUT + ch * 4);
        float* d = &tl[row * 129 + ch * 4];
        d[0] = v[0]; d[1] = v[1]; d[2] = v[2]; d[3] = v[3];
    }
    __syncthreads();
    char* dimg = wsb + W_OFF2 + (long)((e * NS2 + y) * KST + kst) * AIMG;
#pragma unroll
    for (int i = 0; i < 4; ++i) {
        int u = t + i * 256;             // 0..1023
        int cl = u >> 3, kc8 = u & 7;    // cl: local col 0..127
        union { __bf16 h8[8]; uint4 u4; } c;
#pragma unroll
        for (int j = 0; j < 8; ++j) c.h8[j] = (__bf16)tl[(kc8 * 8 + j) * 129 + cl];
        int cc = hh * 128 + cl;
        int slot = (((cc & 1) << 2) | (kc8 & 3)) ^ ((cc >> 1) & 7);
        *(uint4*)(dimg + (kc8 >> 2) * 16384 + ((cc >> 1) << 7) + (slot << 4)) = c.u4;
    }
}

// ---------- 256x256 GEMM: UNPINNED schedule + register-double-buffered ----
// fragments. One vmcnt(0)+barrier per K-tile. No lgkmcnt(0)/sched_barrier/
// setprio pinning: the compiler emits fine-grained lgkmcnt(N) so slice s+1's
// ds_reads overlap slice s's MFMA within each wave (breaks the read->MFMA
// convoy measured as 5570 ~= 3080(LDS) + 2480(MFMA) serialized cycles).

__global__ __launch_bounds__(512, 1) void SwitchLinear_gemm_kernel(
    const char* __restrict__ wsb, const int* __restrict__ ws,
    float* __restrict__ out) {
    const int bid = blockIdx.x;
    const int lb  = (bid & 7) * ((NT2 * NS2) / 8) + (bid >> 3);
    const int tx  = lb % NT2;
    const int y   = lb / NT2;
    if (tx >= ws[0]) return;
    const int e = ws[8 + tx], rs = ws[96 + tx], rows = ws[192 + tx];

    __shared__ __align__(16) char ldsA[2][2][16384]; // [buf][ks]  64KB
    __shared__ __align__(16) char ldsB[2][2][16384]; // [buf][ks]  64KB
    __shared__ int ord[256];

    const int t = threadIdx.x;
    if (t < 256) ord[t] = ws[512 + rs + (t < rows ? t : 0)];

    const char* aImg = wsb + X_OFF2 + (long)(tx * KST) * AIMG;
    const char* bImg = wsb + W_OFF2 + (long)((e * NS2 + y) * KST) * AIMG;

    const int lane = t & 63;
    const int wid  = t >> 6;
    const int wr = wid >> 2, wc = wid & 3;   // 2(M) x 4(N) waves; 128x64 each
    const int lm = lane & 15, lk = lane >> 4;

    f32x4 acc[8][4];
#pragma unroll
    for (int i = 0; i < 8; ++i)
#pragma unroll
        for (int j = 0; j < 4; ++j) acc[i][j] = (f32x4){0.f, 0.f, 0.f, 0.f};

    // named fragment double-buffers (static indexing only)
    bf16x8 aaA[4], aaB[4], bbA[4], bbB[4];

#define STGA(ks, half, tt)                                                    \
    __builtin_amdgcn_global_load_lds(                                         \
        (const __attribute__((address_space(1))) uint32_t*)(                  \
            aImg + (long)(tt) * AIMG + (ks) * 16384 + (half) * 8192 + t * 16),\
        (__attribute__((address_space(3))) uint32_t*)(                        \
            &ldsA[(tt) & 1][ks][(half) * 8192 + t * 16]),                     \
        16, 0, 0)

#define STGB(ks, half, tt)                                                    \
    __builtin_amdgcn_global_load_lds(                                         \
        (const __attribute__((address_space(1))) uint32_t*)(                  \
            bImg + (long)(tt) * AIMG + (ks) * 16384 + (half) * 8192 + t * 16),\
        (__attribute__((address_space(3))) uint32_t*)(                        \
            &ldsB[(tt) & 1][ks][(half) * 8192 + t * 16]),                     \
        16, 0, 0)

#define SWB(r) ((((r) >> 1) << 7) + (((((((r) & 1) << 2)) | lk) ^ (((r) >> 1) & 7)) << 4))

#define LDBF(dst, p, ks)                                                      \
    do { _Pragma("unroll")                                                    \
        for (int ni = 0; ni < 4; ++ni) {                                      \
            int cc = wc * 64 + ni * 16 + lm;                                  \
            dst[ni] = *(const bf16x8*)(&ldsB[p][ks][SWB(cc)]);                \
        } } while (0)

#define LDAF(dst, p, ks, mh)                                                  \
    do { _Pragma("unroll")                                                    \
        for (int q = 0; q < 4; ++q) {                                         \
            int rr = wr * 128 + (mh) * 64 + q * 16 + lm;                      \
            dst[q] = *(const bf16x8*)(&ldsA[p][ks][SWB(rr)]);                 \
        } } while (0)

#define MFMA16F(av, bv, mh)                                                   \
    do { _Pragma("unroll")                                                    \
        for (int q = 0; q < 4; ++q)                                           \
            _Pragma("unroll")                                                 \
            for (int ni = 0; ni < 4; ++ni)                                    \
                acc[(mh) * 4 + q][ni] = __builtin_amdgcn_mfma_f32_16x16x32_bf16( \
                    av[q], bv[ni], acc[(mh) * 4 + q][ni], 0, 0, 0);           \
    } while (0)

    // prologue: stage tile 0; drain; one rendezvous.
    STGA(0, 0, 0); STGA(0, 1, 0); STGA(1, 0, 0); STGA(1, 1, 0);
    STGB(0, 0, 0); STGB(0, 1, 0); STGB(1, 0, 0); STGB(1, 1, 0);
    asm volatile("s_waitcnt vmcnt(0)" ::: "memory");
    asm volatile("s_waitcnt lgkmcnt(0)" ::: "memory");
    __builtin_amdgcn_s_barrier();

    // K-tile: 4 slices (ks,mh) = (0,0)(0,1)(1,0)(1,1); fragments for slice
    // s+1 loaded before slice s's MFMA block; compiler inserts partial
    // lgkmcnt waits. STG prefetch spread between slices. One barrier/tile.
    for (int tt = 0; tt < KST; ++tt) {
        const int p  = tt & 1;
        const int nx = tt + 1;
        const bool iA = nx < KST;

        LDBF(bbA, p, 0);
        LDAF(aaA, p, 0, 0);
        if (iA) { STGA(0, 0, nx); STGA(0, 1, nx); }

        LDAF(aaB, p, 0, 1);
        MFMA16F(aaA, bbA, 0);                      // slice (ks0, mh0)
        if (iA) { STGA(1, 0, nx); STGA(1, 1, nx); }

        LDBF(bbB, p, 1);
        LDAF(aaA, p, 1, 0);
        MFMA16F(aaB, bbA, 1);                      // slice (ks0, mh1)
        if (iA) { STGB(0, 0, nx); STGB(0, 1, nx); }

        LDAF(aaB, p, 1, 1);
        MFMA16F(aaA, bbB, 0);                      // slice (ks1, mh0)
        if (iA) { STGB(1, 0, nx); STGB(1, 1, nx); }

        MFMA16F(aaB, bbB, 1);                      // slice (ks1, mh1)

        asm volatile("s_waitcnt vmcnt(0)" ::: "memory");
        __builtin_amdgcn_s_barrier();
    }

    // epilogue: C/D layout col=lane&15, row=(lane>>4)*4+reg; tokens from LDS
#pragma unroll
    for (int mi = 0; mi < 8; ++mi) {
#pragma unroll
        for (int j = 0; j < 4; ++j) {
            int rl = wr * 128 + mi * 16 + lk * 4 + j;
            if (rl < rows) {
                int token = ord[rl];
                float* po = out + (long)token * D_OUT + y * 256 + wc * 64 + lm;
#pragma unroll
                for (int ni = 0; ni < 4; ++ni) po[ni * 16] = acc[mi][ni][j];
            }
        }
    }
#undef STGA
#undef STGB
#undef SWB
#undef LDBF
#undef LDAF
#undef MFMA16F
}

// ---------- fallback (direct fp32, known-good round-1 structure) ----------

__device__ __forceinline__ int fb_a_byte(int r, int kbyte) {
    return r * 128 + (kbyte ^ ((r & 7) << 4));
}
__device__ __forceinline__ int fb_b_byte(int n, int kbyte) {
    int slot = (n ^ (n >> 2)) & 7;
    return n * 128 + (kbyte ^ (slot << 4));
}

__global__ __launch_bounds__(256, 2) void SwitchLinear_gemm_fb_kernel(
    const float* __restrict__ x, const float* __restrict__ w,
    const int* __restrict__ ws, float* __restrict__ out) {
    const int nt = ws[4];
    const int tx = blockIdx.x;
    if (tx >= nt) return;
    const int e    = ws[256 + tx];
    const int rs   = ws[328 + tx];
    const int rows = ws[400 + tx];
    const int col0 = blockIdx.y * 128;

    __shared__ __align__(16) unsigned short As[128 * 64];
    __shared__ __align__(16) unsigned short Bs[128 * 64];
    __shared__ int ord[128];

    const int t = threadIdx.x;
    if (t < 128) {
        int r = (t < rows) ? (rs + t) : rs;
        ord[t] = ws[512 + r];
    }
    __syncthreads();

    const int kq = t & 15;
    const float* pA[8];
    int rowA[8];
#pragma unroll
    for (int i = 0; i < 8; ++i) {
        int r = (t >> 4) + 16 * i;
        rowA[i] = r;
        pA[i] = x + (long)ord[r] * D_IN + kq * 4;
    }
    const float* pB[2];
    int nB[2], kbB[2];
#pragma unroll
    for (int i = 0; i < 2; ++i) {
        int u = t + 256 * i;
        int kgf = u >> 5, q = u & 31;
        kbB[i] = kgf * 4;
        nB[i]  = q * 4;
        pB[i]  = w + (long)e * D_IN * D_OUT + (long)(kgf * 4) * D_OUT + col0 + q * 4;
    }

    const int lane = t & 63;
    const int wid  = t >> 6;
    const int wr = wid >> 1, wc = wid & 1;
    const int lm = lane & 15, lk = lane >> 4;

    f32x4 acc[4][4];
#pragma unroll
    for (int i = 0; i < 4; ++i)
#pragma unroll
        for (int j = 0; j < 4; ++j) acc[i][j] = (f32x4){0.f, 0.f, 0.f, 0.f};

    for (int k0 = 0; k0 < D_IN; k0 += 64) {
#pragma unroll
        for (int i = 0; i < 8; ++i) {
            f32x4 v = *(const f32x4*)(pA[i] + k0);
            union { __bf16 h[4]; uint2 u; } c;
            c.h[0] = (__bf16)v[0]; c.h[1] = (__bf16)v[1];
            c.h[2] = (__bf16)v[2]; c.h[3] = (__bf16)v[3];
            *(uint2*)((char*)As + fb_a_byte(rowA[i], kq * 8)) = c.u;
        }
#pragma unroll
        for (int i = 0; i < 2; ++i) {
            const float* p = pB[i] + (long)k0 * D_OUT;
            f32x4 r0 = *(const f32x4*)(p);
            f32x4 r1 = *(const f32x4*)(p + D_OUT);
            f32x4 r2 = *(const f32x4*)(p + 2 * D_OUT);
            f32x4 r3 = *(const f32x4*)(p + 3 * D_OUT);
#pragma unroll
            for (int j = 0; j < 4; ++j) {
                int n = nB[i] + j;
                union { __bf16 h[4]; uint2 u; } c;
                c.h[0] = (__bf16)r0[j]; c.h[1] = (__bf16)r1[j];
                c.h[2] = (__bf16)r2[j]; c.h[3] = (__bf16)r3[j];
                *(uint2*)((char*)Bs + fb_b_byte(n, kbB[i] * 2)) = c.u;
            }
        }
        __syncthreads();
#pragma unroll
        for (int ks = 0; ks < 2; ++ks) {
            bf16x8 a[4], b[4];
            const int kbyte = ks * 64 + lk * 16;
#pragma unroll
            for (int mi = 0; mi < 4; ++mi) {
                int r = wr * 64 + mi * 16 + lm;
                a[mi] = *(const bf16x8*)((const char*)As + fb_a_byte(r, kbyte));
            }
#pragma unroll
            for (int ni = 0; ni < 4; ++ni) {
                int n = wc * 64 + ni * 16 + lm;
                b[ni] = *(const bf16x8*)((const char*)Bs + fb_b_byte(n, kbyte));
            }
#pragma unroll
            for (int mi = 0; mi < 4; ++mi)
#pragma unroll
                for (int ni = 0; ni < 4; ++ni)
                    acc[mi][ni] = __builtin_amdgcn_mfma_f32_16x16x32_bf16(
                        a[mi], b[ni], acc[mi][ni], 0, 0, 0);
        }
        __syncthreads();
    }
#pragma unroll
    for (int mi = 0; mi < 4; ++mi) {
#pragma unroll
        for (int j = 0; j < 4; ++j) {
            int rl = wr * 64 + mi * 16 + lk * 4 + j;
            if (rl < rows) {
                int token = ord[rl];
                float* po = out + (long)token * D_OUT + col0 + wc * 64 + lm;
#pragma unroll
                for (int ni = 0; ni < 4; ++ni) po[ni * 16] = acc[mi][ni][j];
            }
        }
    }
}

extern "C" void kernel_launch(void* const* d_in, const int* in_sizes, int n_in,
                              void* d_out, int out_size, void* d_ws, size_t ws_size,
                              hipStream_t stream) {
    const float* x   = (const float*)d_in[0];
    const float* w   = (const float*)d_in[1];
    const int*   idx = (const int*)d_in[2];
    float* out = (float*)d_out;
    int*   ws  = (int*)d_ws;
    char*  wsb = (char*)d_ws;

    SwitchLinear_setup_kernel<<<1, 256, 0, stream>>>(idx, ws);
    if (ws_size >= WS_NEED2) {
        SwitchLinear_convx_kernel<<<dim3(NT2, KST), 256, 0, stream>>>(x, ws, wsb);
        SwitchLinear_convw_kernel<<<NEXP * 64 * KST, 256, 0, stream>>>(w, wsb);
        SwitchLinear_gemm_kernel<<<NT2 * NS2, 512, 0, stream>>>(wsb, ws, out);
    } else {
        dim3 grid(72, 64);
        SwitchLinear_gemm_fb_kernel<<<grid, 256, 0, stream>>>(x, w, ws, out);
    }
}

// Round 15
// 550.753 us; speedup vs baseline: 1.0908x; 1.0908x over previous
//
#include <hip/hip_runtime.h>
#include <hip/hip_bf16.h>
#include <stdint.h>

#define N_TOK 8192
#define D_IN  2048
#define D_OUT 8192
#define NEXP  8
#define KST   32                /* D_IN / 64 */
#define NT2   40                /* max 256-row tiles */
#define NS2   32                /* 256-col strips */
#define AIMG  32768             /* one (tile|strip, kstep) image: [ks][pair-swizzled 16KB] */
#define X_OFF2 65536
#define X_BYTES2 ((long)NT2 * KST * AIMG)                /* 40 MB  */
#define W_OFF2 (X_OFF2 + X_BYTES2)
#define W_BYTES2 ((long)NEXP * NS2 * KST * AIMG)         /* 256 MB */
#define WS_NEED2 ((size_t)(W_OFF2 + W_BYTES2))
#define NWIMG (NEXP * 64 * KST)  /* 8192 convw blocks */

// pair-row swizzle: element (r 0..255, chunk c 0..3 [16B=8 k-elems], ks)
// byte = ks*16384 + (r>>1)*128 + ((((r&1)<<2)|c) ^ ((r>>1)&7))*16
// read group (16 lanes, r=C..C+15, fixed c): 8 slots x2 -> 2-way = free (measured 0)

typedef float  f32x4  __attribute__((ext_vector_type(4)));
typedef __bf16 bf16x8 __attribute__((ext_vector_type(8)));

__global__ void SwitchLinear_setup_kernel(const int* __restrict__ idx,
                                          int* __restrict__ ws) {
    __shared__ int cnt[NEXP], cur[NEXP];
    int t = threadIdx.x;
    if (t < NEXP) cnt[t] = 0;
    __syncthreads();
    for (int i = t; i < N_TOK; i += 256) atomicAdd(&cnt[idx[i]], 1);
    __syncthreads();
    if (t == 0) {
        int o = 0, nt = 0, nt1 = 0;
        for (int e = 0; e < NEXP; ++e) {
            cur[e] = o;
            int c = cnt[e];
            for (int r = 0; r < c; r += 256) {
                ws[8 + nt]   = e;
                ws[96 + nt]  = o + r;
                ws[192 + nt] = (c - r < 256) ? (c - r) : 256;
                ++nt;
            }
            for (int r = 0; r < c; r += 128) {
                ws[256 + nt1] = e;
                ws[328 + nt1] = o + r;
                ws[400 + nt1] = (c - r < 128) ? (c - r) : 128;
                ++nt1;
            }
            o += c;
        }
        ws[0] = nt;
        ws[4] = nt1;
    }
    __syncthreads();
    for (int i = t; i < N_TOK; i += 256) {
        int p = atomicAdd(&cur[idx[i]], 1);
        ws[512 + p] = i;
    }
}

// ---------- fused conversion: blocks [0,8192) convert W, [8192,9472) convert x
__global__ __launch_bounds__(256) void SwitchLinear_conv_kernel(
    const float* __restrict__ x, const float* __restrict__ w,
    const int* __restrict__ ws, char* __restrict__ wsb) {
    const int bidx = blockIdx.x;
    const int t = threadIdx.x;
    if (bidx < NWIMG) {
        // ---- convw body: image index = bidx = (e, strip128 s, kst)
        const int img = bidx;
        const int kst = img & 31, s = (img >> 5) & 63, e = img >> 11;
        const int y = s >> 1, hh = s & 1;
        __shared__ float tl[64 * 129];
        const float* src = w + (long)e * D_IN * D_OUT + (long)(kst * 64) * D_OUT +
                           y * 256 + hh * 128;
#pragma unroll
        for (int i = 0; i < 8; ++i) {
            int u = t + i * 256;
            int row = u >> 5, ch = u & 31;   // 64 k-rows x 128 cols (fp32)
            f32x4 v = *(const f32x4*)(src + (long)row * D_OUT + ch * 4);
            float* d = &tl[row * 129 + ch * 4];
            d[0] = v[0]; d[1] = v[1]; d[2] = v[2]; d[3] = v[3];
        }
        __syncthreads();
        char* dimg = wsb + W_OFF2 + (long)((e * NS2 + y) * KST + kst) * AIMG;
#pragma unroll
        for (int i = 0; i < 4; ++i) {
            int u = t + i * 256;             // 0..1023
            int cl = u >> 3, kc8 = u & 7;    // cl: local col 0..127
            union { __bf16 h8[8]; uint4 u4; } c;
#pragma unroll
            for (int j = 0; j < 8; ++j) c.h8[j] = (__bf16)tl[(kc8 * 8 + j) * 129 + cl];
            int cc = hh * 128 + cl;
            int slot = (((cc & 1) << 2) | (kc8 & 3)) ^ ((cc >> 1) & 7);
            *(uint4*)(dimg + (kc8 >> 2) * 16384 + ((cc >> 1) << 7) + (slot << 4)) = c.u4;
        }
    } else {
        // ---- convx body: u2 = bidx-8192 -> tile = u2%40, kst = u2/40
        const int u2 = bidx - NWIMG;
        const int tile = u2 % NT2, kst = u2 / NT2;
        if (tile >= ws[0]) return;
        const int rs = ws[96 + tile], rows = ws[192 + tile];
        char* img = wsb + X_OFF2 + (long)(tile * KST + kst) * AIMG;
#pragma unroll
        for (int i = 0; i < 8; ++i) {
            int u = t + i * 256;            // 0..2047
            int R = u >> 3, kc8 = u & 7;
            int rl = rs + (R < rows ? R : rows - 1);
            int token = ws[512 + rl];
            const float* src = x + (long)token * D_IN + kst * 64 + kc8 * 8;
            f32x4 v0 = *(const f32x4*)src;
            f32x4 v1 = *(const f32x4*)(src + 4);
            union { __bf16 hh[8]; uint4 u4; } c;
            c.hh[0] = (__bf16)v0[0]; c.hh[1] = (__bf16)v0[1];
            c.hh[2] = (__bf16)v0[2]; c.hh[3] = (__bf16)v0[3];
            c.hh[4] = (__bf16)v1[0]; c.hh[5] = (__bf16)v1[1];
            c.hh[6] = (__bf16)v1[2]; c.hh[7] = (__bf16)v1[3];
            int slot = (((R & 1) << 2) | (kc8 & 3)) ^ ((R >> 1) & 7);
            *(uint4*)(img + (kc8 >> 2) * 16384 + ((R >> 1) << 7) + (slot << 4)) = c.u4;
        }
    }
}

// ---------- 256x256 8-phase GEMM: R8-exact (best measured: 353 us) --------

__global__ __launch_bounds__(512, 1) void SwitchLinear_gemm_kernel(
    const char* __restrict__ wsb, const int* __restrict__ ws,
    float* __restrict__ out) {
    const int bid = blockIdx.x;
    const int lb  = (bid & 7) * ((NT2 * NS2) / 8) + (bid >> 3);
    const int tx  = lb % NT2;
    const int y   = lb / NT2;
    if (tx >= ws[0]) return;
    const int e = ws[8 + tx], rs = ws[96 + tx], rows = ws[192 + tx];

    __shared__ __align__(16) char lds[2][2][2][16384]; // [buf][A=0/B=1][ks]
    __shared__ int ord[256];

    const int t = threadIdx.x;
    if (t < 256) ord[t] = ws[512 + rs + (t < rows ? t : 0)];
    __syncthreads();

    const char* aImg = wsb + X_OFF2 + (long)(tx * KST) * AIMG;
    const char* bImg = wsb + W_OFF2 + (long)((e * NS2 + y) * KST) * AIMG;

    const int lane = t & 63;
    const int wid  = t >> 6;
    const int wr = wid >> 2, wc = wid & 3;   // 2(M) x 4(N) waves; 128x64 each
    const int lm = lane & 15, lk = lane >> 4;

    f32x4 acc[8][4];
#pragma unroll
    for (int i = 0; i < 8; ++i)
#pragma unroll
        for (int j = 0; j < 4; ++j) acc[i][j] = (f32x4){0.f, 0.f, 0.f, 0.f};

    bf16x8 aa[4], bb[4];

#define STG(op, ks, half, tt)                                                 \
    __builtin_amdgcn_global_load_lds(                                         \
        (const __attribute__((address_space(1))) uint32_t*)(                  \
            ((op) ? bImg : aImg) + (long)(tt) * AIMG + (ks) * 16384 +         \
            (half) * 8192 + t * 16),                                          \
        (__attribute__((address_space(3))) uint32_t*)(                        \
            &lds[(tt) & 1][op][ks][(half) * 8192 + t * 16]),                  \
        16, 0, 0)

#define SWB(r) ((((r) >> 1) << 7) + (((((((r) & 1) << 2)) | lk) ^ (((r) >> 1) & 7)) << 4))

#define LDB(p, ks)                                                            \
    do { _Pragma("unroll")                                                    \
        for (int ni = 0; ni < 4; ++ni) {                                      \
            int cc = wc * 64 + ni * 16 + lm;                                  \
            bb[ni] = *(const bf16x8*)(&lds[p][1][ks][SWB(cc)]);               \
        } } while (0)

#define LDA(p, ks, mh)                                                        \
    do { _Pragma("unroll")                                                    \
        for (int q = 0; q < 4; ++q) {                                         \
            int rr = wr * 128 + (mh) * 64 + q * 16 + lm;                      \
            aa[q] = *(const bf16x8*)(&lds[p][0][ks][SWB(rr)]);                \
        } } while (0)

#define MFMA16(mh)                                                            \
    do { _Pragma("unroll")                                                    \
        for (int q = 0; q < 4; ++q)                                           \
            _Pragma("unroll")                                                 \
            for (int ni = 0; ni < 4; ++ni)                                    \
                acc[(mh) * 4 + q][ni] = __builtin_amdgcn_mfma_f32_16x16x32_bf16( \
                    aa[q], bb[ni], acc[(mh) * 4 + q][ni], 0, 0, 0);           \
    } while (0)

#define PH(p, ks, mh, DOB, ISSUE, POST)                                       \
    do {                                                                      \
        if (DOB) LDB(p, ks);                                                  \
        LDA(p, ks, mh);                                                       \
        ISSUE;                                                                \
        __builtin_amdgcn_s_barrier();                                         \
        asm volatile("s_waitcnt lgkmcnt(0)" ::: "memory");                    \
        __builtin_amdgcn_sched_barrier(0);                                    \
        __builtin_amdgcn_s_setprio(1);                                        \
        MFMA16(mh);                                                           \
        __builtin_amdgcn_s_setprio(0);                                        \
        POST;                                                                 \
        __builtin_amdgcn_s_barrier();                                         \
    } while (0)

    // prologue: stage tile 0 fully (ks0 A,B then ks1 A,B)
    STG(0, 0, 0, 0); STG(0, 0, 1, 0); STG(1, 0, 0, 0); STG(1, 0, 1, 0);
    STG(0, 1, 0, 0); STG(0, 1, 1, 0); STG(1, 1, 0, 0); STG(1, 1, 1, 0);
    asm volatile("s_waitcnt vmcnt(4)" ::: "memory");   // tile0 ks0 resident
    __builtin_amdgcn_s_barrier();

    // steady state (spread issue, late waits): ph2-POST vmcnt(4) retires this
    // tile's ks1 (consumed ph3); ph4-POST vmcnt(4) retires next tile's ks0
    // (consumed next ph1). Outstanding never drains below 4.
    for (int tt = 0; tt < KST - 1; ++tt) {
        const int p = tt & 1;
        const int nx = tt + 1;
        PH(p, 0, 0, 1, { STG(0, 0, 0, nx); STG(0, 0, 1, nx); }, ((void)0));
        PH(p, 0, 1, 0, { STG(1, 0, 0, nx); STG(1, 0, 1, nx); },
           asm volatile("s_waitcnt vmcnt(4)" ::: "memory"));
        PH(p, 1, 0, 1, { STG(0, 1, 0, nx); STG(0, 1, 1, nx); }, ((void)0));
        PH(p, 1, 1, 0, { STG(1, 1, 0, nx); STG(1, 1, 1, nx); },
           asm volatile("s_waitcnt vmcnt(4)" ::: "memory"));
    }
    {   // peeled last tile: nothing to stage; drain own ks1 after ph2's MFMA
        const int p = (KST - 1) & 1;
        PH(p, 0, 0, 1, ((void)0), ((void)0));
        PH(p, 0, 1, 0, ((void)0),
           asm volatile("s_waitcnt vmcnt(0)" ::: "memory"));
        PH(p, 1, 0, 1, ((void)0), ((void)0));
        PH(p, 1, 1, 0, ((void)0), ((void)0));
    }

    // epilogue: C/D layout col=lane&15, row=(lane>>4)*4+reg
#pragma unroll
    for (int mi = 0; mi < 8; ++mi) {
#pragma unroll
        for (int j = 0; j < 4; ++j) {
            int rl = wr * 128 + mi * 16 + lk * 4 + j;
            if (rl < rows) {
                int token = ord[rl];
                float* po = out + (long)token * D_OUT + y * 256 + wc * 64 + lm;
#pragma unroll
                for (int ni = 0; ni < 4; ++ni) po[ni * 16] = acc[mi][ni][j];
            }
        }
    }
#undef STG
#undef SWB
#undef LDB
#undef LDA
#undef MFMA16
#undef PH
}

// ---------- fallback (direct fp32, known-good round-1 structure) ----------

__device__ __forceinline__ int fb_a_byte(int r, int kbyte) {
    return r * 128 + (kbyte ^ ((r & 7) << 4));
}
__device__ __forceinline__ int fb_b_byte(int n, int kbyte) {
    int slot = (n ^ (n >> 2)) & 7;
    return n * 128 + (kbyte ^ (slot << 4));
}

__global__ __launch_bounds__(256, 2) void SwitchLinear_gemm_fb_kernel(
    const float* __restrict__ x, const float* __restrict__ w,
    const int* __restrict__ ws, float* __restrict__ out) {
    const int nt = ws[4];
    const int tx = blockIdx.x;
    if (tx >= nt) return;
    const int e    = ws[256 + tx];
    const int rs   = ws[328 + tx];
    const int rows = ws[400 + tx];
    const int col0 = blockIdx.y * 128;

    __shared__ __align__(16) unsigned short As[128 * 64];
    __shared__ __align__(16) unsigned short Bs[128 * 64];
    __shared__ int ord[128];

    const int t = threadIdx.x;
    if (t < 128) {
        int r = (t < rows) ? (rs + t) : rs;
        ord[t] = ws[512 + r];
    }
    __syncthreads();

    const int kq = t & 15;
    const float* pA[8];
    int rowA[8];
#pragma unroll
    for (int i = 0; i < 8; ++i) {
        int r = (t >> 4) + 16 * i;
        rowA[i] = r;
        pA[i] = x + (long)ord[r] * D_IN + kq * 4;
    }
    const float* pB[2];
    int nB[2], kbB[2];
#pragma unroll
    for (int i = 0; i < 2; ++i) {
        int u = t + 256 * i;
        int kgf = u >> 5, q = u & 31;
        kbB[i] = kgf * 4;
        nB[i]  = q * 4;
        pB[i]  = w + (long)e * D_IN * D_OUT + (long)(kgf * 4) * D_OUT + col0 + q * 4;
    }

    const int lane = t & 63;
    const int wid  = t >> 6;
    const int wr = wid >> 1, wc = wid & 1;
    const int lm = lane & 15, lk = lane >> 4;

    f32x4 acc[4][4];
#pragma unroll
    for (int i = 0; i < 4; ++i)
#pragma unroll
        for (int j = 0; j < 4; ++j) acc[i][j] = (f32x4){0.f, 0.f, 0.f, 0.f};

    for (int k0 = 0; k0 < D_IN; k0 += 64) {
#pragma unroll
        for (int i = 0; i < 8; ++i) {
            f32x4 v = *(const f32x4*)(pA[i] + k0);
            union { __bf16 h[4]; uint2 u; } c;
            c.h[0] = (__bf16)v[0]; c.h[1] = (__bf16)v[1];
            c.h[2] = (__bf16)v[2]; c.h[3] = (__bf16)v[3];
            *(uint2*)((char*)As + fb_a_byte(rowA[i], kq * 8)) = c.u;
        }
#pragma unroll
        for (int i = 0; i < 2; ++i) {
            const float* p = pB[i] + (long)k0 * D_OUT;
            f32x4 r0 = *(const f32x4*)(p);
            f32x4 r1 = *(const f32x4*)(p + D_OUT);
            f32x4 r2 = *(const f32x4*)(p + 2 * D_OUT);
            f32x4 r3 = *(const f32x4*)(p + 3 * D_OUT);
#pragma unroll
            for (int j = 0; j < 4; ++j) {
                int n = nB[i] + j;
                union { __bf16 h[4]; uint2 u; } c;
                c.h[0] = (__bf16)r0[j]; c.h[1] = (__bf16)r1[j];
                c.h[2] = (__bf16)r2[j]; c.h[3] = (__bf16)r3[j];
                *(uint2*)((char*)Bs + fb_b_byte(n, kbB[i] * 2)) = c.u;
            }
        }
        __syncthreads();
#pragma unroll
        for (int ks = 0; ks < 2; ++ks) {
            bf16x8 a[4], b[4];
            const int kbyte = ks * 64 + lk * 16;
#pragma unroll
            for (int mi = 0; mi < 4; ++mi) {
                int r = wr * 64 + mi * 16 + lm;
                a[mi] = *(const bf16x8*)((const char*)As + fb_a_byte(r, kbyte));
            }
#pragma unroll
            for (int ni = 0; ni < 4; ++ni) {
                int n = wc * 64 + ni * 16 + lm;
                b[ni] = *(const bf16x8*)((const char*)Bs + fb_b_byte(n, kbyte));
            }
#pragma unroll
            for (int mi = 0; mi < 4; ++mi)
#pragma unroll
                for (int ni = 0; ni < 4; ++ni)
                    acc[mi][ni] = __builtin_amdgcn_mfma_f32_16x16x32_bf16(
                        a[mi], b[ni], acc[mi][ni], 0, 0, 0);
        }
        __syncthreads();
    }
#pragma unroll
    for (int mi = 0; mi < 4; ++mi) {
#pragma unroll
        for (int j = 0; j < 4; ++j) {
            int rl = wr * 64 + mi * 16 + lk * 4 + j;
            if (rl < rows) {
                int token = ord[rl];
                float* po = out + (long)token * D_OUT + col0 + wc * 64 + lm;
#pragma unroll
                for (int ni = 0; ni < 4; ++ni) po[ni * 16] = acc[mi][ni][j];
            }
        }
    }
}

extern "C" void kernel_launch(void* const* d_in, const int* in_sizes, int n_in,
                              void* d_out, int out_size, void* d_ws, size_t ws_size,
                              hipStream_t stream) {
    const float* x   = (const float*)d_in[0];
    const float* w   = (const float*)d_in[1];
    const int*   idx = (const int*)d_in[2];
    float* out = (float*)d_out;
    int*   ws  = (int*)d_ws;
    char*  wsb = (char*)d_ws;

    SwitchLinear_setup_kernel<<<1, 256, 0, stream>>>(idx, ws);
    if (ws_size >= WS_NEED2) {
        SwitchLinear_conv_kernel<<<NWIMG + NT2 * KST, 256, 0, stream>>>(x, w, ws, wsb);
        SwitchLinear_gemm_kernel<<<NT2 * NS2, 512, 0, stream>>>(wsb, ws, out);
    } else {
        dim3 grid(72, 64);
        SwitchLinear_gemm_fb_kernel<<<grid, 256, 0, stream>>>(x, w, ws, out);
    }
}